// Round 1
// 4999.957 us; speedup vs baseline: 1.2278x; 1.2278x over previous
//
#include <hip/hip_runtime.h>
#include <math.h>

#define DD 512
#define SS 1024
#define BB 4
#define HH 8
#define DFF 2048
#define LL 4
#define NT 4096           // BB*SS
#define EPSF 1e-5f

// ---------------- workspace layout (float elements) ----------------
#define O_X0    ((size_t)0)            // 2,097,152  emb+pe
#define O_X1    ((size_t)2097152)      // 2,097,152  conv out / current x
#define O_HSEQ  ((size_t)4194304)      // (unused this version)
#define O_CTX   ((size_t)6293504)      // 2,097,152 (ctx)
#define O_QKV   ((size_t)8390656)      // 6,291,456
#define O_BIG   ((size_t)14682112)     // 16,777,216 (lstm gates 8.39M low half /
                                       //   h-pack pairs 4.2M*2 floats upper half / scores 16M / ffh 8M)
#define O_BSUM  ((size_t)31459328)     // 2048

__device__ __forceinline__ float sigf(float x){ return 1.0f/(1.0f+expf(-x)); }

// ---------------- embedding + sinusoidal PE ----------------
__global__ void k_embed(const int* __restrict__ src, const float* __restrict__ emb,
                        float* __restrict__ x){
  int idx = blockIdx.x*256 + threadIdx.x;
  if (idx >= NT*DD) return;
  int d = idx & (DD-1);
  int n = idx >> 9;          // b*SS + s
  int s = n & (SS-1);
  int tok = src[n];
  int i2 = d & ~1;
  float div = expf(-(float)i2 * (9.210340371976184f/512.0f));  // ln(10000)/512
  float ang = (float)s * div;
  float pe = (d & 1) ? cosf(ang) : sinf(ang);
  x[idx] = emb[(size_t)tok*DD + d]*22.62741699796952f + pe;    // sqrt(512)
}

// ---------------- depthwise conv k=3 + BN(eval) + ReLU ----------------
__global__ void k_conv(const float* __restrict__ x, const float* __restrict__ cw,
                       const float* __restrict__ cb, const float* __restrict__ bg,
                       const float* __restrict__ bb, const float* __restrict__ bm,
                       const float* __restrict__ bv, float* __restrict__ y){
  int idx = blockIdx.x*256 + threadIdx.x;
  if (idx >= NT*DD) return;
  int d = idx & (DD-1);
  int n = idx >> 9;
  int s = n & (SS-1);
  float acc = cb[d];
  if (s > 0)     acc += x[idx - DD]*cw[d*3+0];
  acc += x[idx]*cw[d*3+1];
  if (s < SS-1)  acc += x[idx + DD]*cw[d*3+2];
  float v = (acc - bm[d])*rsqrtf(bv[d]+EPSF)*bg[d] + bb[d];
  y[idx] = fmaxf(v, 0.0f);
}

__global__ void k_bsum(const float* a, const float* b, float* o, int n){
  int i = blockIdx.x*256 + threadIdx.x;
  if (i < n) o[i] = a[i] + b[i];
}

// ---------------- generic SIMT f32 GEMM: C[M,N] = A[M,K] @ W[N,K]^T + bias ----------------
template<int BM, int BN, int BK, int TM, int TN, int ACT>
__global__ __launch_bounds__(256) void k_gemm(const float* __restrict__ A,
                                              const float* __restrict__ W,
                                              const float* __restrict__ bias,
                                              float* __restrict__ C,
                                              int M, int N, int K){
  __shared__ float As[BK][BM+4];
  __shared__ float Ws[BK][BN+4];
  const int tid = threadIdx.x;
  const int nbx = N / BN;
  const int bx = blockIdx.x % nbx;
  const int by = blockIdx.x / nbx;
  const int m0 = by*BM, n0 = bx*BN;
  const int tx = tid % (BN/TN);
  const int ty = tid / (BN/TN);
  float acc[TM][TN] = {};
  for (int k0 = 0; k0 < K; k0 += BK){
    #pragma unroll
    for (int e = 0; e < (BM*BK)/256; ++e){
      int lin = e*256 + tid;
      int kk = lin % BK, m = lin / BK;
      As[kk][m] = A[(size_t)(m0+m)*K + k0+kk];
    }
    #pragma unroll
    for (int e = 0; e < (BN*BK)/256; ++e){
      int lin = e*256 + tid;
      int kk = lin % BK, n = lin / BK;
      Ws[kk][n] = W[(size_t)(n0+n)*K + k0+kk];
    }
    __syncthreads();
    #pragma unroll
    for (int kk = 0; kk < BK; ++kk){
      float ra[TM], rb[TN];
      #pragma unroll
      for (int i=0;i<TM;i++) ra[i] = As[kk][ty*TM+i];
      #pragma unroll
      for (int j=0;j<TN;j++) rb[j] = Ws[kk][tx*TN+j];
      #pragma unroll
      for (int i=0;i<TM;i++)
        #pragma unroll
        for (int j=0;j<TN;j++)
          acc[i][j] += ra[i]*rb[j];
    }
    __syncthreads();
  }
  #pragma unroll
  for (int i=0;i<TM;i++){
    int m = m0 + ty*TM + i;
    #pragma unroll
    for (int j=0;j<TN;j++){
      int n = n0 + tx*TN + j;
      float v = acc[i][j] + bias[n];
      if (ACT == 1) v = 0.5f*v*(1.0f + erff(v*0.70710678118654752f));  // exact gelu
      C[(size_t)m*N + n] = v;
    }
  }
}

// ---------------- persistent LSTM: 256 blocks = 4 batches x 64 chunks(8 dims) ----------------
// Dataflow sync: each h element is stored as a single 64-bit relaxed agent-scope
// atomic {tag = t+1 (hi32) | h bits (lo32)}. Readers poll the pairs directly —
// the ready flag and the payload arrive in the same atomic word, so there is no
// counter, no RMW contention, no vmcnt drain, and no second load round trip.
// Slots are write-once per step (region memset to 0 each launch; tag 0 == h(0)=0),
// so blocks are flow-controlled purely by the data dependency.
__global__ __launch_bounds__(256) void k_lstm(const float* __restrict__ gates_in,
                                              const float* __restrict__ w_hh,
                                              unsigned long long* __restrict__ hpack){
  __shared__ float hsh[DD];
  __shared__ float gl[32];
  const int b = blockIdx.x >> 6;
  const int chunk = blockIdx.x & 63;
  const int d0 = chunk*8;
  const int tid = threadIdx.x;
  const int r = tid >> 3;        // 0..31 : local row = gate*8 + di
  const int ks = tid & 7;        // interleaved k-slice: this lane covers k = j*8+ks
  const int gate = r >> 3;
  const int di = r & 7;
  float w[64];
  {
    const float* wrow = w_hh + (size_t)(gate*DD + d0 + di)*DD;
    #pragma unroll
    for (int j=0;j<64;j++) w[j] = wrow[j*8 + ks];
  }
  float c = 0.0f;
  const float* gbase = gates_in + (size_t)(b*SS)*(4*DD) + gate*DD + d0 + di;
  for (int t=0; t<SS; ++t){
    // issue gate-bias load early (normal, L2-cached); consumed at gl write
    float gv = 0.0f;
    if (ks == 0) gv = gbase[(size_t)t*(4*DD)];
    // poll the packed (tag,h) pairs for timestep t
    unsigned long long* hp = hpack + (size_t)(t*BB + b)*DD;
    const unsigned long long exp_tag = (unsigned long long)t;
    unsigned long long p0 = __hip_atomic_load(hp + tid,       __ATOMIC_RELAXED, __HIP_MEMORY_SCOPE_AGENT);
    unsigned long long p1 = __hip_atomic_load(hp + tid + 256, __ATOMIC_RELAXED, __HIP_MEMORY_SCOPE_AGENT);
    while ((p0 >> 32) != exp_tag || (p1 >> 32) != exp_tag){
      __builtin_amdgcn_s_sleep(1);
      if ((p0 >> 32) != exp_tag)
        p0 = __hip_atomic_load(hp + tid,       __ATOMIC_RELAXED, __HIP_MEMORY_SCOPE_AGENT);
      if ((p1 >> 32) != exp_tag)
        p1 = __hip_atomic_load(hp + tid + 256, __ATOMIC_RELAXED, __HIP_MEMORY_SCOPE_AGENT);
    }
    union { unsigned int u; float f; } u0, u1;
    u0.u = (unsigned int)p0;
    u1.u = (unsigned int)p1;
    hsh[tid]       = u0.f;
    hsh[tid + 256] = u1.f;
    __syncthreads();
    float acc = 0.0f;
    #pragma unroll
    for (int j=0;j<64;j++) acc += w[j]*hsh[j*8 + ks];   // 8 consecutive banks + broadcast: conflict-free
    acc += __shfl_down(acc, 4, 8);
    acc += __shfl_down(acc, 2, 8);
    acc += __shfl_down(acc, 1, 8);
    if (ks == 0) gl[r] = acc + gv;
    __syncthreads();
    if (tid < 8){
      float gi = sigf(gl[tid]);
      float gf = sigf(gl[8 + tid]);
      float gg = tanhf(gl[16 + tid]);
      float go = sigf(gl[24 + tid]);
      c = gf*c + gi*gg;
      float h = go*tanhf(c);
      union { float f; unsigned int u; } hu; hu.f = h;
      unsigned long long pk = ((unsigned long long)(unsigned int)(t+1) << 32)
                            | (unsigned long long)hu.u;
      __hip_atomic_store(&hpack[(size_t)((t+1)*BB + b)*DD + d0 + tid], pk,
                         __ATOMIC_RELAXED, __HIP_MEMORY_SCOPE_AGENT);
    }
    // no trailing barrier needed: next iteration's hsh writes don't conflict with
    // gl reads (disjoint LDS), and next gl write happens only after the next
    // __syncthreads(), which tid<8 reach after finishing their gl reads.
  }
}

__global__ void k_resid(float* __restrict__ x, const unsigned long long* __restrict__ hpack){
  int idx = blockIdx.x*256 + threadIdx.x;
  if (idx >= NT*DD) return;
  int d = idx & (DD-1);
  int n = idx >> 9;
  int s = n & (SS-1);
  int b = n >> 10;
  union { unsigned int u; float f; } hu;
  hu.u = (unsigned int)hpack[(size_t)((s+1)*BB + b)*DD + d];
  x[idx] += hu.f;
}

// ---------------- attention: scores = (Q*scale) @ K^T  (per half-batch) ----------------
__global__ __launch_bounds__(256) void k_scores(const float* __restrict__ qkv,
                                                float* __restrict__ sc, int bbase){
  __shared__ float Qs[64][65];
  __shared__ float Ks[64][65];
  const int tid = threadIdx.x;
  const int kt = blockIdx.x & 15;
  const int qt = (blockIdx.x >> 4) & 15;
  const int h  = (blockIdx.x >> 8) & 7;
  const int hb = (blockIdx.x >> 11) & 1;
  const int b = bbase + hb;
  const int q0 = qt*64, k0 = kt*64;
  #pragma unroll
  for (int e=0;e<16;e++){
    int lin = e*256 + tid;
    int d = lin & 63, rr = lin >> 6;
    Qs[rr][d] = qkv[(size_t)(b*SS + q0+rr)*1536 + h*64 + d] * 0.125f;
    Ks[rr][d] = qkv[(size_t)(b*SS + k0+rr)*1536 + DD + h*64 + d];
  }
  __syncthreads();
  const int tx = tid & 15, ty = tid >> 4;
  float acc[4][4] = {};
  #pragma unroll
  for (int kk=0;kk<64;kk++){
    float ra[4], rb[4];
    #pragma unroll
    for (int i=0;i<4;i++) ra[i] = Qs[ty*4+i][kk];
    #pragma unroll
    for (int j=0;j<4;j++) rb[j] = Ks[tx*4+j][kk];
    #pragma unroll
    for (int i=0;i<4;i++)
      #pragma unroll
      for (int j=0;j<4;j++)
        acc[i][j] += ra[i]*rb[j];
  }
  float* out = sc + (size_t)(hb*HH + h)*SS*SS;
  #pragma unroll
  for (int i=0;i<4;i++)
    #pragma unroll
    for (int j=0;j<4;j++)
      out[(size_t)(q0+ty*4+i)*SS + k0+tx*4+j] = acc[i][j];
}

__device__ __forceinline__ float blockReduce(float v, float* red, int tid, int isMax){
  #pragma unroll
  for (int o=32;o>0;o>>=1){
    float t = __shfl_xor(v, o);
    v = isMax ? fmaxf(v, t) : v + t;
  }
  if ((tid & 63) == 0) red[tid >> 6] = v;
  __syncthreads();
  float r = red[0];
  #pragma unroll
  for (int i=1;i<4;i++) r = isMax ? fmaxf(r, red[i]) : r + red[i];
  __syncthreads();
  return r;
}

// softmax rows in place + accumulate head-average into d_out attn region
__global__ __launch_bounds__(256) void k_softmax(float* __restrict__ sc,
                                                 float* __restrict__ attn_out,
                                                 int l, int bbase){
  __shared__ float avg[SS];
  __shared__ float red[8];
  const int tid = threadIdx.x;
  const int q  = blockIdx.x & (SS-1);
  const int hb = blockIdx.x >> 10;
  const int b = bbase + hb;
  for (int j=tid;j<SS;j+=256) avg[j] = 0.0f;
  __syncthreads();
  for (int h=0;h<HH;h++){
    float* row = sc + (size_t)(hb*HH + h)*SS*SS + (size_t)q*SS;
    float v[4];
    float m = -1e30f;
    #pragma unroll
    for (int j=0;j<4;j++){ v[j] = row[tid + j*256]; m = fmaxf(m, v[j]); }
    m = blockReduce(m, red, tid, 1);
    float s = 0.0f;
    #pragma unroll
    for (int j=0;j<4;j++){ v[j] = expf(v[j] - m); s += v[j]; }
    s = blockReduce(s, red, tid, 0);
    float inv = 1.0f/s;
    #pragma unroll
    for (int j=0;j<4;j++){
      float p = v[j]*inv;
      row[tid + j*256] = p;
      avg[tid + j*256] += p;
    }
    __syncthreads();
  }
  float* ao = attn_out + (size_t)((l*BB + b)*SS + q)*SS;
  for (int j=tid;j<SS;j+=256) ao[j] = avg[j]*0.125f;
}

// ctx[:, h*64 .. ] = P @ V
__global__ __launch_bounds__(256) void k_pv(const float* __restrict__ sc,
                                            const float* __restrict__ qkv,
                                            float* __restrict__ ctx, int bbase){
  __shared__ float Ps[64][17];
  __shared__ float Vs[16][65];
  const int tid = threadIdx.x;
  const int qt = blockIdx.x & 15;
  const int h  = (blockIdx.x >> 4) & 7;
  const int hb = (blockIdx.x >> 7) & 1;
  const int b = bbase + hb;
  const int q0 = qt*64;
  const float* P = sc + (size_t)(hb*HH + h)*SS*SS;
  const int tx = tid & 15, ty = tid >> 4;
  float acc[4][4] = {};
  for (int k0=0;k0<SS;k0+=16){
    #pragma unroll
    for (int e=0;e<4;e++){
      int lin = e*256 + tid;
      int kk = lin & 15, rr = lin >> 4;
      Ps[rr][kk] = P[(size_t)(q0+rr)*SS + k0+kk];
    }
    #pragma unroll
    for (int e=0;e<4;e++){
      int lin = e*256 + tid;
      int d = lin & 63, k = lin >> 6;
      Vs[k][d] = qkv[(size_t)(b*SS + k0+k)*1536 + 1024 + h*64 + d];
    }
    __syncthreads();
    #pragma unroll
    for (int kk=0;kk<16;kk++){
      float ra[4], rb[4];
      #pragma unroll
      for (int i=0;i<4;i++) ra[i] = Ps[ty*4+i][kk];
      #pragma unroll
      for (int j=0;j<4;j++) rb[j] = Vs[kk][tx*4+j];
      #pragma unroll
      for (int i=0;i<4;i++)
        #pragma unroll
        for (int j=0;j<4;j++)
          acc[i][j] += ra[i]*rb[j];
    }
    __syncthreads();
  }
  #pragma unroll
  for (int i=0;i<4;i++)
    #pragma unroll
    for (int j=0;j<4;j++)
      ctx[(size_t)(b*SS + q0+ty*4+i)*DD + h*64 + tx*4+j] = acc[i][j];
}

// ---------------- LayerNorm: out = LN(x (+ y)) * g + b ----------------
__global__ __launch_bounds__(64) void k_ln(const float* __restrict__ x,
                                           const float* __restrict__ y,
                                           const float* __restrict__ g,
                                           const float* __restrict__ bta,
                                           float* __restrict__ out){
  const int n = blockIdx.x;
  const int tid = threadIdx.x;
  float v[8];
  float s = 0.0f, sq = 0.0f;
  #pragma unroll
  for (int j=0;j<8;j++){
    int d = j*64 + tid;
    float a = x[(size_t)n*DD + d];
    if (y) a += y[(size_t)n*DD + d];
    v[j] = a; s += a; sq += a*a;
  }
  #pragma unroll
  for (int o=32;o>0;o>>=1){ s += __shfl_xor(s, o); sq += __shfl_xor(sq, o); }
  float mean = s*(1.0f/DD);
  float var = sq*(1.0f/DD) - mean*mean;
  float rstd = rsqrtf(var + EPSF);
  #pragma unroll
  for (int j=0;j<8;j++){
    int d = j*64 + tid;
    out[(size_t)n*DD + d] = (v[j]-mean)*rstd*g[d] + bta[d];
  }
}

extern "C" void kernel_launch(void* const* d_in, const int* in_sizes, int n_in,
                              void* d_out, int out_size, void* d_ws, size_t ws_size,
                              hipStream_t stream){
  const int*   src    = (const int*)  d_in[0];
  const float* emb    = (const float*)d_in[1];
  const float* conv_w = (const float*)d_in[2];
  const float* conv_b = (const float*)d_in[3];
  const float* bn_g   = (const float*)d_in[4];
  const float* bn_b   = (const float*)d_in[5];
  const float* bn_m   = (const float*)d_in[6];
  const float* bn_v   = (const float*)d_in[7];
  const float* w_ih   = (const float*)d_in[8];
  const float* w_hh   = (const float*)d_in[9];
  const float* b_ih   = (const float*)d_in[10];
  const float* b_hh   = (const float*)d_in[11];
  const float* in_w   = (const float*)d_in[12];
  const float* in_b   = (const float*)d_in[13];
  const float* out_w  = (const float*)d_in[14];
  const float* out_b  = (const float*)d_in[15];
  const float* ln1_g  = (const float*)d_in[16];
  const float* ln1_b  = (const float*)d_in[17];
  const float* w1     = (const float*)d_in[18];
  const float* b1     = (const float*)d_in[19];
  const float* w2     = (const float*)d_in[20];
  const float* b2     = (const float*)d_in[21];
  const float* ln2_g  = (const float*)d_in[22];
  const float* ln2_b  = (const float*)d_in[23];
  const float* fin_g  = (const float*)d_in[24];
  const float* fin_b  = (const float*)d_in[25];

  float* ws    = (float*)d_ws;
  float* x0    = ws + O_X0;
  float* x1    = ws + O_X1;
  float* ctx   = ws + O_CTX;
  float* qkv   = ws + O_QKV;
  float* big   = ws + O_BIG;     // gates (low 8.39M) / scores / ffh
  float* bsum  = ws + O_BSUM;
  // packed (tag,h) pairs live in the upper half of BIG: gates occupy exactly
  // NT*4*DD = 8,388,608 floats; pairs need (SS+1)*BB*DD*2 = 4,198,400 floats.
  // Scores reuse the full BIG region, but only after k_resid has consumed h.
  unsigned long long* hpack = (unsigned long long*)(big + 8388608);

  float* outx  = (float*)d_out;            // [B,S,D]
  float* attn  = outx + (size_t)NT*DD;     // [L,B,S,S]

  // zero tags (+ h(0)=0): slot0 tag 0 == expected tag at t=0
  hipMemsetAsync(hpack, 0, (size_t)(SS+1)*BB*DD*sizeof(unsigned long long), stream);

  const int eb = (NT*DD)/256;
  k_embed<<<eb, 256, 0, stream>>>(src, emb, x0);
  k_conv <<<eb, 256, 0, stream>>>(x0, conv_w, conv_b, bn_g, bn_b, bn_m, bn_v, x1);
  k_bsum <<<8, 256, 0, stream>>>(b_ih, b_hh, bsum, 4*DD);

  // LSTM input precompute: gates = x1 @ w_ih^T + (b_ih + b_hh)
  k_gemm<128,128,16,8,8,0><<<(NT/128)*((4*DD)/128), 256, 0, stream>>>(
      x1, w_ih, bsum, big, NT, 4*DD, DD);
  k_lstm<<<256, 256, 0, stream>>>(big, w_hh, hpack);
  k_resid<<<eb, 256, 0, stream>>>(x1, hpack);

  float* cur = x1;
  float* tmp = x0;
  for (int l=0; l<LL; ++l){
    // qkv = cur @ in_w[l]^T + in_b[l]
    k_gemm<128,128,16,8,8,0><<<(NT/128)*(1536/128), 256, 0, stream>>>(
        cur, in_w + (size_t)l*1536*DD, in_b + (size_t)l*1536, qkv, NT, 1536, DD);
    for (int bb2=0; bb2<2; ++bb2){
      int bbase = bb2*2;
      k_scores <<<4096, 256, 0, stream>>>(qkv, big, bbase);
      k_softmax<<<2048, 256, 0, stream>>>(big, attn, l, bbase);
      k_pv     <<<256,  256, 0, stream>>>(big, qkv, ctx, bbase);
    }
    // proj: tmp = ctx @ out_w[l]^T + out_b[l]
    k_gemm<64,64,16,4,4,0><<<(NT/64)*(DD/64), 256, 0, stream>>>(
        ctx, out_w + (size_t)l*DD*DD, out_b + (size_t)l*DD, tmp, NT, DD, DD);
    k_ln<<<NT, 64, 0, stream>>>(cur, tmp, ln1_g + l*DD, ln1_b + l*DD, cur);
    // ffh = gelu(cur @ w1[l]^T + b1[l])
    k_gemm<128,128,16,8,8,1><<<(NT/128)*(DFF/128), 256, 0, stream>>>(
        cur, w1 + (size_t)l*DFF*DD, b1 + (size_t)l*DFF, big, NT, DFF, DD);
    // tmp = ffh @ w2[l]^T + b2[l]
    k_gemm<64,64,16,4,4,0><<<(NT/64)*(DD/64), 256, 0, stream>>>(
        big, w2 + (size_t)l*DD*DFF, b2 + (size_t)l*DD, tmp, NT, DD, DFF);
    k_ln<<<NT, 64, 0, stream>>>(cur, tmp, ln2_g + l*DD, ln2_b + l*DD, cur);
  }
  k_ln<<<NT, 64, 0, stream>>>(cur, nullptr, fin_g, fin_b, outx);
}

// Round 2
// 4080.842 us; speedup vs baseline: 1.5043x; 1.2252x over previous
//
#include <hip/hip_runtime.h>
#include <math.h>

#define DD 512
#define SS 1024
#define BB 4
#define HH 8
#define DFF 2048
#define LL 4
#define NT 4096           // BB*SS
#define EPSF 1e-5f

// ---------------- workspace layout (float elements) ----------------
#define O_X0    ((size_t)0)            // 2,097,152  emb+pe
#define O_X1    ((size_t)2097152)      // 2,097,152  conv out / current x
#define O_HSEQ  ((size_t)4194304)      // (unused this version)
#define O_CTX   ((size_t)6293504)      // 2,097,152 (ctx)
#define O_QKV   ((size_t)8390656)      // 6,291,456
#define O_BIG   ((size_t)14682112)     // 16,777,216 (lstm gates 8.39M low half /
                                       //   h-pack pairs upper half / scores 16M / ffh 8M)
#define O_BSUM  ((size_t)31459328)     // 2048

typedef __attribute__((ext_vector_type(8))) _Float16 f16x8;
typedef __attribute__((ext_vector_type(4))) _Float16 f16x4;
typedef __attribute__((ext_vector_type(4))) float    f32x4;

__device__ __forceinline__ float sigf(float x){ return 1.0f/(1.0f+expf(-x)); }

// ---------------- embedding + sinusoidal PE ----------------
__global__ void k_embed(const int* __restrict__ src, const float* __restrict__ emb,
                        float* __restrict__ x){
  int idx = blockIdx.x*256 + threadIdx.x;
  if (idx >= NT*DD) return;
  int d = idx & (DD-1);
  int n = idx >> 9;          // b*SS + s
  int s = n & (SS-1);
  int tok = src[n];
  int i2 = d & ~1;
  float div = expf(-(float)i2 * (9.210340371976184f/512.0f));  // ln(10000)/512
  float ang = (float)s * div;
  float pe = (d & 1) ? cosf(ang) : sinf(ang);
  x[idx] = emb[(size_t)tok*DD + d]*22.62741699796952f + pe;    // sqrt(512)
}

// ---------------- depthwise conv k=3 + BN(eval) + ReLU ----------------
__global__ void k_conv(const float* __restrict__ x, const float* __restrict__ cw,
                       const float* __restrict__ cb, const float* __restrict__ bg,
                       const float* __restrict__ bb, const float* __restrict__ bm,
                       const float* __restrict__ bv, float* __restrict__ y){
  int idx = blockIdx.x*256 + threadIdx.x;
  if (idx >= NT*DD) return;
  int d = idx & (DD-1);
  int n = idx >> 9;
  int s = n & (SS-1);
  float acc = cb[d];
  if (s > 0)     acc += x[idx - DD]*cw[d*3+0];
  acc += x[idx]*cw[d*3+1];
  if (s < SS-1)  acc += x[idx + DD]*cw[d*3+2];
  float v = (acc - bm[d])*rsqrtf(bv[d]+EPSF)*bg[d] + bb[d];
  y[idx] = fmaxf(v, 0.0f);
}

__global__ void k_bsum(const float* a, const float* b, float* o, int n){
  int i = blockIdx.x*256 + threadIdx.x;
  if (i < n) o[i] = a[i] + b[i];
}

// ---------------- MFMA split-f16 GEMM: C[M,N] = A[M,K] @ W[N,K]^T + bias ----------------
// f32 operands decomposed as hi(f16)+lo(f16); C = Ah*Wh + Ah*Wl + Al*Wh (f32 acc).
// Error ~2^-18 relative -- far below harness tolerance.
// Tile: 128x128, BK=32, 4 waves in 2x2, each wave 64x64 = 4x4 fragments of 16x16x32.
#define BKP 40   // padded K stride in halves (80B, 16B-aligned rows, ~2-way banks)
template<int ACT>
__global__ __launch_bounds__(256) void k_gemm_mfma(const float* __restrict__ A,
                                                   const float* __restrict__ W,
                                                   const float* __restrict__ bias,
                                                   float* __restrict__ C,
                                                   int M, int N, int K){
  __shared__ _Float16 Ah[128][BKP];
  __shared__ _Float16 Al[128][BKP];
  __shared__ _Float16 Wh[128][BKP];
  __shared__ _Float16 Wl[128][BKP];
  const int tid = threadIdx.x;
  const int nbx = N >> 7;
  const int bx = blockIdx.x % nbx;
  const int by = blockIdx.x / nbx;
  const int m0 = by << 7, n0 = bx << 7;
  const int lane = tid & 63;
  const int wid  = tid >> 6;
  const int wr = wid >> 1, wc = wid & 1;      // wave tile (64x64) position
  const int fm = lane & 15, fg = lane >> 4;   // fragment row/col + k-group

  f32x4 acc[4][4];
  #pragma unroll
  for (int i=0;i<4;i++)
    #pragma unroll
    for (int j=0;j<4;j++) acc[i][j] = (f32x4){0.0f,0.0f,0.0f,0.0f};

  for (int k0 = 0; k0 < K; k0 += 32){
    // stage A and W tiles as (hi,lo) f16 pairs; float4 global loads
    #pragma unroll
    for (int e = 0; e < 4; ++e){
      int lin = e*256 + tid;
      int rr = lin >> 3;
      int k4 = (lin & 7) << 2;
      float4 av = *reinterpret_cast<const float4*>(A + (size_t)(m0+rr)*K + k0 + k4);
      float4 wv = *reinterpret_cast<const float4*>(W + (size_t)(n0+rr)*K + k0 + k4);
      f16x4 ahv, alv, whv, wlv;
      _Float16 h;
      h = (_Float16)av.x; ahv[0]=h; alv[0]=(_Float16)(av.x-(float)h);
      h = (_Float16)av.y; ahv[1]=h; alv[1]=(_Float16)(av.y-(float)h);
      h = (_Float16)av.z; ahv[2]=h; alv[2]=(_Float16)(av.z-(float)h);
      h = (_Float16)av.w; ahv[3]=h; alv[3]=(_Float16)(av.w-(float)h);
      *reinterpret_cast<f16x4*>(&Ah[rr][k4]) = ahv;
      *reinterpret_cast<f16x4*>(&Al[rr][k4]) = alv;
      h = (_Float16)wv.x; whv[0]=h; wlv[0]=(_Float16)(wv.x-(float)h);
      h = (_Float16)wv.y; whv[1]=h; wlv[1]=(_Float16)(wv.y-(float)h);
      h = (_Float16)wv.z; whv[2]=h; wlv[2]=(_Float16)(wv.z-(float)h);
      h = (_Float16)wv.w; whv[3]=h; wlv[3]=(_Float16)(wv.w-(float)h);
      *reinterpret_cast<f16x4*>(&Wh[rr][k4]) = whv;
      *reinterpret_cast<f16x4*>(&Wl[rr][k4]) = wlv;
    }
    __syncthreads();
    f16x8 a_h[4], a_l[4], w_h[4], w_l[4];
    #pragma unroll
    for (int i=0;i<4;i++){
      int row = wr*64 + i*16 + fm;
      a_h[i] = *reinterpret_cast<const f16x8*>(&Ah[row][fg*8]);
      a_l[i] = *reinterpret_cast<const f16x8*>(&Al[row][fg*8]);
    }
    #pragma unroll
    for (int j=0;j<4;j++){
      int row = wc*64 + j*16 + fm;
      w_h[j] = *reinterpret_cast<const f16x8*>(&Wh[row][fg*8]);
      w_l[j] = *reinterpret_cast<const f16x8*>(&Wl[row][fg*8]);
    }
    #pragma unroll
    for (int i=0;i<4;i++)
      #pragma unroll
      for (int j=0;j<4;j++){
        acc[i][j] = __builtin_amdgcn_mfma_f32_16x16x32_f16(a_h[i], w_h[j], acc[i][j], 0, 0, 0);
        acc[i][j] = __builtin_amdgcn_mfma_f32_16x16x32_f16(a_h[i], w_l[j], acc[i][j], 0, 0, 0);
        acc[i][j] = __builtin_amdgcn_mfma_f32_16x16x32_f16(a_l[i], w_h[j], acc[i][j], 0, 0, 0);
      }
    __syncthreads();
  }
  // epilogue: C mapping col=lane&15, row=(lane>>4)*4+reg  [m89-verified]
  #pragma unroll
  for (int i=0;i<4;i++){
    #pragma unroll
    for (int r=0;r<4;r++){
      int row = m0 + wr*64 + i*16 + fg*4 + r;
      #pragma unroll
      for (int j=0;j<4;j++){
        int col = n0 + wc*64 + j*16 + fm;
        float v = acc[i][j][r] + bias[col];
        if (ACT == 1) v = 0.5f*v*(1.0f + erff(v*0.70710678118654752f));  // exact gelu
        C[(size_t)row*N + col] = v;
      }
    }
  }
}

// ---------------- persistent LSTM: 256 blocks = 4 batches x 64 chunks(8 dims) ----------------
// Dataflow sync via packed 64-bit {tag|h} relaxed agent-scope atomics (see R1 notes).
__global__ __launch_bounds__(256) void k_lstm(const float* __restrict__ gates_in,
                                              const float* __restrict__ w_hh,
                                              unsigned long long* __restrict__ hpack){
  __shared__ float hsh[DD];
  __shared__ float gl[32];
  const int b = blockIdx.x >> 6;
  const int chunk = blockIdx.x & 63;
  const int d0 = chunk*8;
  const int tid = threadIdx.x;
  const int r = tid >> 3;        // 0..31 : local row = gate*8 + di
  const int ks = tid & 7;        // interleaved k-slice: this lane covers k = j*8+ks
  const int gate = r >> 3;
  const int di = r & 7;
  float w[64];
  {
    const float* wrow = w_hh + (size_t)(gate*DD + d0 + di)*DD;
    #pragma unroll
    for (int j=0;j<64;j++) w[j] = wrow[j*8 + ks];
  }
  float c = 0.0f;
  const float* gbase = gates_in + (size_t)(b*SS)*(4*DD) + gate*DD + d0 + di;
  for (int t=0; t<SS; ++t){
    float gv = 0.0f;
    if (ks == 0) gv = gbase[(size_t)t*(4*DD)];
    unsigned long long* hp = hpack + (size_t)(t*BB + b)*DD;
    const unsigned long long exp_tag = (unsigned long long)t;
    unsigned long long p0 = __hip_atomic_load(hp + tid,       __ATOMIC_RELAXED, __HIP_MEMORY_SCOPE_AGENT);
    unsigned long long p1 = __hip_atomic_load(hp + tid + 256, __ATOMIC_RELAXED, __HIP_MEMORY_SCOPE_AGENT);
    while ((p0 >> 32) != exp_tag || (p1 >> 32) != exp_tag){
      __builtin_amdgcn_s_sleep(1);
      if ((p0 >> 32) != exp_tag)
        p0 = __hip_atomic_load(hp + tid,       __ATOMIC_RELAXED, __HIP_MEMORY_SCOPE_AGENT);
      if ((p1 >> 32) != exp_tag)
        p1 = __hip_atomic_load(hp + tid + 256, __ATOMIC_RELAXED, __HIP_MEMORY_SCOPE_AGENT);
    }
    union { unsigned int u; float f; } u0, u1;
    u0.u = (unsigned int)p0;
    u1.u = (unsigned int)p1;
    hsh[tid]       = u0.f;
    hsh[tid + 256] = u1.f;
    __syncthreads();
    float a0=0.0f, a1=0.0f, a2=0.0f, a3=0.0f;
    #pragma unroll
    for (int j=0;j<64;j+=4){
      a0 += w[j+0]*hsh[(j+0)*8 + ks];
      a1 += w[j+1]*hsh[(j+1)*8 + ks];
      a2 += w[j+2]*hsh[(j+2)*8 + ks];
      a3 += w[j+3]*hsh[(j+3)*8 + ks];
    }
    float acc = (a0+a1)+(a2+a3);
    acc += __shfl_down(acc, 4, 8);
    acc += __shfl_down(acc, 2, 8);
    acc += __shfl_down(acc, 1, 8);
    if (ks == 0) gl[r] = acc + gv;
    __syncthreads();
    if (tid < 8){
      float gi = sigf(gl[tid]);
      float gf = sigf(gl[8 + tid]);
      float gg = tanhf(gl[16 + tid]);
      float go = sigf(gl[24 + tid]);
      c = gf*c + gi*gg;
      float h = go*tanhf(c);
      union { float f; unsigned int u; } hu; hu.f = h;
      unsigned long long pk = ((unsigned long long)(unsigned int)(t+1) << 32)
                            | (unsigned long long)hu.u;
      __hip_atomic_store(&hpack[(size_t)((t+1)*BB + b)*DD + d0 + tid], pk,
                         __ATOMIC_RELAXED, __HIP_MEMORY_SCOPE_AGENT);
    }
  }
}

__global__ void k_resid(float* __restrict__ x, const unsigned long long* __restrict__ hpack){
  int idx = blockIdx.x*256 + threadIdx.x;
  if (idx >= NT*DD) return;
  int d = idx & (DD-1);
  int n = idx >> 9;
  int s = n & (SS-1);
  int b = n >> 10;
  union { unsigned int u; float f; } hu;
  hu.u = (unsigned int)hpack[(size_t)((s+1)*BB + b)*DD + d];
  x[idx] += hu.f;
}

// ---------------- attention: scores = (Q*scale) @ K^T  (per half-batch) ----------------
__global__ __launch_bounds__(256) void k_scores(const float* __restrict__ qkv,
                                                float* __restrict__ sc, int bbase){
  __shared__ float Qs[64][65];
  __shared__ float Ks[64][65];
  const int tid = threadIdx.x;
  const int kt = blockIdx.x & 15;
  const int qt = (blockIdx.x >> 4) & 15;
  const int h  = (blockIdx.x >> 8) & 7;
  const int hb = (blockIdx.x >> 11) & 1;
  const int b = bbase + hb;
  const int q0 = qt*64, k0 = kt*64;
  #pragma unroll
  for (int e=0;e<16;e++){
    int lin = e*256 + tid;
    int d = lin & 63, rr = lin >> 6;
    Qs[rr][d] = qkv[(size_t)(b*SS + q0+rr)*1536 + h*64 + d] * 0.125f;
    Ks[rr][d] = qkv[(size_t)(b*SS + k0+rr)*1536 + DD + h*64 + d];
  }
  __syncthreads();
  const int tx = tid & 15, ty = tid >> 4;
  float acc[4][4] = {};
  #pragma unroll
  for (int kk=0;kk<64;kk++){
    float ra[4], rb[4];
    #pragma unroll
    for (int i=0;i<4;i++) ra[i] = Qs[ty*4+i][kk];
    #pragma unroll
    for (int j=0;j<4;j++) rb[j] = Ks[tx*4+j][kk];
    #pragma unroll
    for (int i=0;i<4;i++)
      #pragma unroll
      for (int j=0;j<4;j++)
        acc[i][j] += ra[i]*rb[j];
  }
  float* out = sc + (size_t)(hb*HH + h)*SS*SS;
  #pragma unroll
  for (int i=0;i<4;i++)
    #pragma unroll
    for (int j=0;j<4;j++)
      out[(size_t)(q0+ty*4+i)*SS + k0+tx*4+j] = acc[i][j];
}

__device__ __forceinline__ float blockReduce(float v, float* red, int tid, int isMax){
  #pragma unroll
  for (int o=32;o>0;o>>=1){
    float t = __shfl_xor(v, o);
    v = isMax ? fmaxf(v, t) : v + t;
  }
  if ((tid & 63) == 0) red[tid >> 6] = v;
  __syncthreads();
  float r = red[0];
  #pragma unroll
  for (int i=1;i<4;i++) r = isMax ? fmaxf(r, red[i]) : r + red[i];
  __syncthreads();
  return r;
}

// softmax rows in place + accumulate head-average into d_out attn region
__global__ __launch_bounds__(256) void k_softmax(float* __restrict__ sc,
                                                 float* __restrict__ attn_out,
                                                 int l, int bbase){
  __shared__ float avg[SS];
  __shared__ float red[8];
  const int tid = threadIdx.x;
  const int q  = blockIdx.x & (SS-1);
  const int hb = blockIdx.x >> 10;
  const int b = bbase + hb;
  for (int j=tid;j<SS;j+=256) avg[j] = 0.0f;
  __syncthreads();
  for (int h=0;h<HH;h++){
    float* row = sc + (size_t)(hb*HH + h)*SS*SS + (size_t)q*SS;
    float v[4];
    float m = -1e30f;
    #pragma unroll
    for (int j=0;j<4;j++){ v[j] = row[tid + j*256]; m = fmaxf(m, v[j]); }
    m = blockReduce(m, red, tid, 1);
    float s = 0.0f;
    #pragma unroll
    for (int j=0;j<4;j++){ v[j] = expf(v[j] - m); s += v[j]; }
    s = blockReduce(s, red, tid, 0);
    float inv = 1.0f/s;
    #pragma unroll
    for (int j=0;j<4;j++){
      float p = v[j]*inv;
      row[tid + j*256] = p;
      avg[tid + j*256] += p;
    }
    __syncthreads();
  }
  float* ao = attn_out + (size_t)((l*BB + b)*SS + q)*SS;
  for (int j=tid;j<SS;j+=256) ao[j] = avg[j]*0.125f;
}

// ctx[:, h*64 .. ] = P @ V
__global__ __launch_bounds__(256) void k_pv(const float* __restrict__ sc,
                                            const float* __restrict__ qkv,
                                            float* __restrict__ ctx, int bbase){
  __shared__ float Ps[64][17];
  __shared__ float Vs[16][65];
  const int tid = threadIdx.x;
  const int qt = blockIdx.x & 15;
  const int h  = (blockIdx.x >> 4) & 7;
  const int hb = (blockIdx.x >> 7) & 1;
  const int b = bbase + hb;
  const int q0 = qt*64;
  const float* P = sc + (size_t)(hb*HH + h)*SS*SS;
  const int tx = tid & 15, ty = tid >> 4;
  float acc[4][4] = {};
  for (int k0=0;k0<SS;k0+=16){
    #pragma unroll
    for (int e=0;e<4;e++){
      int lin = e*256 + tid;
      int kk = lin & 15, rr = lin >> 4;
      Ps[rr][kk] = P[(size_t)(q0+rr)*SS + k0+kk];
    }
    #pragma unroll
    for (int e=0;e<4;e++){
      int lin = e*256 + tid;
      int d = lin & 63, k = lin >> 6;
      Vs[k][d] = qkv[(size_t)(b*SS + k0+k)*1536 + 1024 + h*64 + d];
    }
    __syncthreads();
    #pragma unroll
    for (int kk=0;kk<16;kk++){
      float ra[4], rb[4];
      #pragma unroll
      for (int i=0;i<4;i++) ra[i] = Ps[ty*4+i][kk];
      #pragma unroll
      for (int j=0;j<4;j++) rb[j] = Vs[kk][tx*4+j];
      #pragma unroll
      for (int i=0;i<4;i++)
        #pragma unroll
        for (int j=0;j<4;j++)
          acc[i][j] += ra[i]*rb[j];
    }
    __syncthreads();
  }
  #pragma unroll
  for (int i=0;i<4;i++)
    #pragma unroll
    for (int j=0;j<4;j++)
      ctx[(size_t)(b*SS + q0+ty*4+i)*DD + h*64 + tx*4+j] = acc[i][j];
}

// ---------------- LayerNorm: out = LN(x (+ y)) * g + b ----------------
__global__ __launch_bounds__(64) void k_ln(const float* __restrict__ x,
                                           const float* __restrict__ y,
                                           const float* __restrict__ g,
                                           const float* __restrict__ bta,
                                           float* __restrict__ out){
  const int n = blockIdx.x;
  const int tid = threadIdx.x;
  float v[8];
  float s = 0.0f, sq = 0.0f;
  #pragma unroll
  for (int j=0;j<8;j++){
    int d = j*64 + tid;
    float a = x[(size_t)n*DD + d];
    if (y) a += y[(size_t)n*DD + d];
    v[j] = a; s += a; sq += a*a;
  }
  #pragma unroll
  for (int o=32;o>0;o>>=1){ s += __shfl_xor(s, o); sq += __shfl_xor(sq, o); }
  float mean = s*(1.0f/DD);
  float var = sq*(1.0f/DD) - mean*mean;
  float rstd = rsqrtf(var + EPSF);
  #pragma unroll
  for (int j=0;j<8;j++){
    int d = j*64 + tid;
    out[(size_t)n*DD + d] = (v[j]-mean)*rstd*g[d] + bta[d];
  }
}

extern "C" void kernel_launch(void* const* d_in, const int* in_sizes, int n_in,
                              void* d_out, int out_size, void* d_ws, size_t ws_size,
                              hipStream_t stream){
  const int*   src    = (const int*)  d_in[0];
  const float* emb    = (const float*)d_in[1];
  const float* conv_w = (const float*)d_in[2];
  const float* conv_b = (const float*)d_in[3];
  const float* bn_g   = (const float*)d_in[4];
  const float* bn_b   = (const float*)d_in[5];
  const float* bn_m   = (const float*)d_in[6];
  const float* bn_v   = (const float*)d_in[7];
  const float* w_ih   = (const float*)d_in[8];
  const float* w_hh   = (const float*)d_in[9];
  const float* b_ih   = (const float*)d_in[10];
  const float* b_hh   = (const float*)d_in[11];
  const float* in_w   = (const float*)d_in[12];
  const float* in_b   = (const float*)d_in[13];
  const float* out_w  = (const float*)d_in[14];
  const float* out_b  = (const float*)d_in[15];
  const float* ln1_g  = (const float*)d_in[16];
  const float* ln1_b  = (const float*)d_in[17];
  const float* w1     = (const float*)d_in[18];
  const float* b1     = (const float*)d_in[19];
  const float* w2     = (const float*)d_in[20];
  const float* b2     = (const float*)d_in[21];
  const float* ln2_g  = (const float*)d_in[22];
  const float* ln2_b  = (const float*)d_in[23];
  const float* fin_g  = (const float*)d_in[24];
  const float* fin_b  = (const float*)d_in[25];

  float* ws    = (float*)d_ws;
  float* x0    = ws + O_X0;
  float* x1    = ws + O_X1;
  float* ctx   = ws + O_CTX;
  float* qkv   = ws + O_QKV;
  float* big   = ws + O_BIG;     // gates (low 8.39M) / scores / ffh
  float* bsum  = ws + O_BSUM;
  // packed (tag,h) pairs in the upper half of BIG (gates use the low 8,388,608 floats;
  // scores reuse full BIG only after k_resid has consumed h).
  unsigned long long* hpack = (unsigned long long*)(big + 8388608);

  float* outx  = (float*)d_out;            // [B,S,D]
  float* attn  = outx + (size_t)NT*DD;     // [L,B,S,S]

  hipMemsetAsync(hpack, 0, (size_t)(SS+1)*BB*DD*sizeof(unsigned long long), stream);

  const int eb = (NT*DD)/256;
  k_embed<<<eb, 256, 0, stream>>>(src, emb, x0);
  k_conv <<<eb, 256, 0, stream>>>(x0, conv_w, conv_b, bn_g, bn_b, bn_m, bn_v, x1);
  k_bsum <<<8, 256, 0, stream>>>(b_ih, b_hh, bsum, 4*DD);

  // LSTM input precompute: gates = x1 @ w_ih^T + (b_ih + b_hh)
  k_gemm_mfma<0><<<(NT/128)*((4*DD)/128), 256, 0, stream>>>(
      x1, w_ih, bsum, big, NT, 4*DD, DD);
  k_lstm<<<256, 256, 0, stream>>>(big, w_hh, hpack);
  k_resid<<<eb, 256, 0, stream>>>(x1, hpack);

  float* cur = x1;
  float* tmp = x0;
  for (int l=0; l<LL; ++l){
    // qkv = cur @ in_w[l]^T + in_b[l]
    k_gemm_mfma<0><<<(NT/128)*(1536/128), 256, 0, stream>>>(
        cur, in_w + (size_t)l*1536*DD, in_b + (size_t)l*1536, qkv, NT, 1536, DD);
    for (int bb2=0; bb2<2; ++bb2){
      int bbase = bb2*2;
      k_scores <<<4096, 256, 0, stream>>>(qkv, big, bbase);
      k_softmax<<<2048, 256, 0, stream>>>(big, attn, l, bbase);
      k_pv     <<<256,  256, 0, stream>>>(big, qkv, ctx, bbase);
    }
    // proj: tmp = ctx @ out_w[l]^T + out_b[l]
    k_gemm_mfma<0><<<(NT/128)*(DD/128), 256, 0, stream>>>(
        ctx, out_w + (size_t)l*DD*DD, out_b + (size_t)l*DD, tmp, NT, DD, DD);
    k_ln<<<NT, 64, 0, stream>>>(cur, tmp, ln1_g + l*DD, ln1_b + l*DD, cur);
    // ffh = gelu(cur @ w1[l]^T + b1[l])
    k_gemm_mfma<1><<<(NT/128)*(DFF/128), 256, 0, stream>>>(
        cur, w1 + (size_t)l*DFF*DD, b1 + (size_t)l*DFF, big, NT, DFF, DD);
    // tmp = ffh @ w2[l]^T + b2[l]
    k_gemm_mfma<0><<<(NT/128)*(DD/128), 256, 0, stream>>>(
        big, w2 + (size_t)l*DD*DFF, b2 + (size_t)l*DD, tmp, NT, DD, DFF);
    k_ln<<<NT, 64, 0, stream>>>(cur, tmp, ln2_g + l*DD, ln2_b + l*DD, cur);
  }
  k_ln<<<NT, 64, 0, stream>>>(cur, nullptr, fin_g, fin_b, outx);
}

// Round 4
// 3468.195 us; speedup vs baseline: 1.7700x; 1.1766x over previous
//
#include <hip/hip_runtime.h>
#include <math.h>

#define DD 512
#define SS 1024
#define BB 4
#define HH 8
#define DFF 2048
#define LL 4
#define NT 4096           // BB*SS
#define EPSF 1e-5f

// ---------------- workspace layout (float elements) ----------------
#define O_X0    ((size_t)0)            // 2,097,152  emb+pe
#define O_X1    ((size_t)2097152)      // 2,097,152  conv out / current x
#define O_HSEQ  ((size_t)4194304)      // (unused this version)
#define O_CTX   ((size_t)6293504)      // 2,097,152 (ctx)
#define O_QKV   ((size_t)8390656)      // 6,291,456
#define O_BIG   ((size_t)14682112)     // 16,777,216 (lstm gates 8.39M low half /
                                       //   h-pack pairs upper half / scores 16M / ffh 8M)
#define O_BSUM  ((size_t)31459328)     // 2048

typedef __attribute__((ext_vector_type(8))) _Float16 f16x8;
typedef __attribute__((ext_vector_type(4))) _Float16 f16x4;
typedef __attribute__((ext_vector_type(4))) float    f32x4;

// fast transcendentals: v_exp_f32 / v_rcp_f32 based (~1e-7 rel, saturating-safe)
__device__ __forceinline__ float fsig(float x){
  return __builtin_amdgcn_rcpf(1.0f + __expf(-x));
}
__device__ __forceinline__ float ftanh(float x){
  return 1.0f - 2.0f*__builtin_amdgcn_rcpf(1.0f + __expf(2.0f*x));
}
struct h2 { _Float16 hi, lo; };
__device__ __forceinline__ h2 split2(float v){
  h2 r; r.hi = (_Float16)v; r.lo = (_Float16)(v - (float)r.hi); return r;
}

// ---------------- embedding + sinusoidal PE ----------------
__global__ void k_embed(const int* __restrict__ src, const float* __restrict__ emb,
                        float* __restrict__ x){
  int idx = blockIdx.x*256 + threadIdx.x;
  if (idx >= NT*DD) return;
  int d = idx & (DD-1);
  int n = idx >> 9;          // b*SS + s
  int s = n & (SS-1);
  int tok = src[n];
  int i2 = d & ~1;
  float div = expf(-(float)i2 * (9.210340371976184f/512.0f));  // ln(10000)/512
  float ang = (float)s * div;
  float pe = (d & 1) ? cosf(ang) : sinf(ang);
  x[idx] = emb[(size_t)tok*DD + d]*22.62741699796952f + pe;    // sqrt(512)
}

// ---------------- depthwise conv k=3 + BN(eval) + ReLU ----------------
__global__ void k_conv(const float* __restrict__ x, const float* __restrict__ cw,
                       const float* __restrict__ cb, const float* __restrict__ bg,
                       const float* __restrict__ bb, const float* __restrict__ bm,
                       const float* __restrict__ bv, float* __restrict__ y){
  int idx = blockIdx.x*256 + threadIdx.x;
  if (idx >= NT*DD) return;
  int d = idx & (DD-1);
  int n = idx >> 9;
  int s = n & (SS-1);
  float acc = cb[d];
  if (s > 0)     acc += x[idx - DD]*cw[d*3+0];
  acc += x[idx]*cw[d*3+1];
  if (s < SS-1)  acc += x[idx + DD]*cw[d*3+2];
  float v = (acc - bm[d])*rsqrtf(bv[d]+EPSF)*bg[d] + bb[d];
  y[idx] = fmaxf(v, 0.0f);
}

__global__ void k_bsum(const float* a, const float* b, float* o, int n){
  int i = blockIdx.x*256 + threadIdx.x;
  if (i < n) o[i] = a[i] + b[i];
}

// ---------------- MFMA split-f16 GEMM: C[M,N] = A[M,K] @ W[N,K]^T + bias ----------------
#define BKP 40   // padded K stride in halves
template<int ACT>
__global__ __launch_bounds__(256) void k_gemm_mfma(const float* __restrict__ A,
                                                   const float* __restrict__ W,
                                                   const float* __restrict__ bias,
                                                   float* __restrict__ C,
                                                   int M, int N, int K){
  __shared__ _Float16 Ah[128][BKP];
  __shared__ _Float16 Al[128][BKP];
  __shared__ _Float16 Wh[128][BKP];
  __shared__ _Float16 Wl[128][BKP];
  const int tid = threadIdx.x;
  const int nbx = N >> 7;
  const int bx = blockIdx.x % nbx;
  const int by = blockIdx.x / nbx;
  const int m0 = by << 7, n0 = bx << 7;
  const int lane = tid & 63;
  const int wid  = tid >> 6;
  const int wr = wid >> 1, wc = wid & 1;
  const int fm = lane & 15, fg = lane >> 4;

  f32x4 acc[4][4];
  #pragma unroll
  for (int i=0;i<4;i++)
    #pragma unroll
    for (int j=0;j<4;j++) acc[i][j] = (f32x4){0.0f,0.0f,0.0f,0.0f};

  for (int k0 = 0; k0 < K; k0 += 32){
    #pragma unroll
    for (int e = 0; e < 4; ++e){
      int lin = e*256 + tid;
      int rr = lin >> 3;
      int k4 = (lin & 7) << 2;
      float4 av = *reinterpret_cast<const float4*>(A + (size_t)(m0+rr)*K + k0 + k4);
      float4 wv = *reinterpret_cast<const float4*>(W + (size_t)(n0+rr)*K + k0 + k4);
      f16x4 ahv, alv, whv, wlv;
      h2 t;
      t = split2(av.x); ahv[0]=t.hi; alv[0]=t.lo;
      t = split2(av.y); ahv[1]=t.hi; alv[1]=t.lo;
      t = split2(av.z); ahv[2]=t.hi; alv[2]=t.lo;
      t = split2(av.w); ahv[3]=t.hi; alv[3]=t.lo;
      *reinterpret_cast<f16x4*>(&Ah[rr][k4]) = ahv;
      *reinterpret_cast<f16x4*>(&Al[rr][k4]) = alv;
      t = split2(wv.x); whv[0]=t.hi; wlv[0]=t.lo;
      t = split2(wv.y); whv[1]=t.hi; wlv[1]=t.lo;
      t = split2(wv.z); whv[2]=t.hi; wlv[2]=t.lo;
      t = split2(wv.w); whv[3]=t.hi; wlv[3]=t.lo;
      *reinterpret_cast<f16x4*>(&Wh[rr][k4]) = whv;
      *reinterpret_cast<f16x4*>(&Wl[rr][k4]) = wlv;
    }
    __syncthreads();
    f16x8 a_h[4], a_l[4], w_h[4], w_l[4];
    #pragma unroll
    for (int i=0;i<4;i++){
      int row = wr*64 + i*16 + fm;
      a_h[i] = *reinterpret_cast<const f16x8*>(&Ah[row][fg*8]);
      a_l[i] = *reinterpret_cast<const f16x8*>(&Al[row][fg*8]);
    }
    #pragma unroll
    for (int j=0;j<4;j++){
      int row = wc*64 + j*16 + fm;
      w_h[j] = *reinterpret_cast<const f16x8*>(&Wh[row][fg*8]);
      w_l[j] = *reinterpret_cast<const f16x8*>(&Wl[row][fg*8]);
    }
    #pragma unroll
    for (int i=0;i<4;i++)
      #pragma unroll
      for (int j=0;j<4;j++){
        acc[i][j] = __builtin_amdgcn_mfma_f32_16x16x32_f16(a_h[i], w_h[j], acc[i][j], 0, 0, 0);
        acc[i][j] = __builtin_amdgcn_mfma_f32_16x16x32_f16(a_h[i], w_l[j], acc[i][j], 0, 0, 0);
        acc[i][j] = __builtin_amdgcn_mfma_f32_16x16x32_f16(a_l[i], w_h[j], acc[i][j], 0, 0, 0);
      }
    __syncthreads();
  }
  #pragma unroll
  for (int i=0;i<4;i++){
    #pragma unroll
    for (int r=0;r<4;r++){
      int row = m0 + wr*64 + i*16 + fg*4 + r;
      #pragma unroll
      for (int j=0;j<4;j++){
        int col = n0 + wc*64 + j*16 + fm;
        float v = acc[i][j][r] + bias[col];
        if (ACT == 1) v = 0.5f*v*(1.0f + erff(v*0.70710678118654752f));  // exact gelu
        C[(size_t)row*N + col] = v;
      }
    }
  }
}

// ---------------- MFMA attention scores: sc = (Q*scale) @ K^T (128x128 tiles) ----------------
#define SPAD 72
__global__ __launch_bounds__(256) void k_scores_mfma(const float* __restrict__ qkv,
                                                     float* __restrict__ sc, int bbase){
  __shared__ _Float16 Qh[128][SPAD], Ql[128][SPAD];
  __shared__ _Float16 Kh[128][SPAD], Kl[128][SPAD];
  const int tid = threadIdx.x;
  const int kt = blockIdx.x & 7;
  const int qt = (blockIdx.x >> 3) & 7;
  const int h  = (blockIdx.x >> 6) & 7;
  const int hb = (blockIdx.x >> 9) & 1;
  const int b  = bbase + hb;
  const int q0 = qt*128, k0 = kt*128;
  #pragma unroll
  for (int e=0;e<8;e++){
    int lin = e*256 + tid;
    int rr = lin >> 4;
    int c4 = (lin & 15) << 2;
    float4 qv = *reinterpret_cast<const float4*>(qkv + (size_t)(b*SS + q0+rr)*1536 + h*64 + c4);
    float4 kv = *reinterpret_cast<const float4*>(qkv + (size_t)(b*SS + k0+rr)*1536 + DD + h*64 + c4);
    qv.x *= 0.125f; qv.y *= 0.125f; qv.z *= 0.125f; qv.w *= 0.125f;
    f16x4 qh, ql, kh, kl;
    h2 t;
    t = split2(qv.x); qh[0]=t.hi; ql[0]=t.lo;
    t = split2(qv.y); qh[1]=t.hi; ql[1]=t.lo;
    t = split2(qv.z); qh[2]=t.hi; ql[2]=t.lo;
    t = split2(qv.w); qh[3]=t.hi; ql[3]=t.lo;
    t = split2(kv.x); kh[0]=t.hi; kl[0]=t.lo;
    t = split2(kv.y); kh[1]=t.hi; kl[1]=t.lo;
    t = split2(kv.z); kh[2]=t.hi; kl[2]=t.lo;
    t = split2(kv.w); kh[3]=t.hi; kl[3]=t.lo;
    *reinterpret_cast<f16x4*>(&Qh[rr][c4]) = qh;
    *reinterpret_cast<f16x4*>(&Ql[rr][c4]) = ql;
    *reinterpret_cast<f16x4*>(&Kh[rr][c4]) = kh;
    *reinterpret_cast<f16x4*>(&Kl[rr][c4]) = kl;
  }
  __syncthreads();
  const int lane = tid & 63, wid = tid >> 6;
  const int wr = wid >> 1, wc = wid & 1;
  const int fm = lane & 15, fg = lane >> 4;
  f32x4 acc[4][4];
  #pragma unroll
  for (int i=0;i<4;i++)
    #pragma unroll
    for (int j=0;j<4;j++) acc[i][j] = (f32x4){0.0f,0.0f,0.0f,0.0f};
  #pragma unroll
  for (int ks=0; ks<2; ks++){
    f16x8 ah[4], al[4], bh[4], bl[4];
    #pragma unroll
    for (int i=0;i<4;i++){
      int row = wr*64 + i*16 + fm;
      ah[i] = *reinterpret_cast<const f16x8*>(&Qh[row][ks*32 + fg*8]);
      al[i] = *reinterpret_cast<const f16x8*>(&Ql[row][ks*32 + fg*8]);
    }
    #pragma unroll
    for (int j=0;j<4;j++){
      int row = wc*64 + j*16 + fm;
      bh[j] = *reinterpret_cast<const f16x8*>(&Kh[row][ks*32 + fg*8]);
      bl[j] = *reinterpret_cast<const f16x8*>(&Kl[row][ks*32 + fg*8]);
    }
    #pragma unroll
    for (int i=0;i<4;i++)
      #pragma unroll
      for (int j=0;j<4;j++){
        acc[i][j] = __builtin_amdgcn_mfma_f32_16x16x32_f16(ah[i], bh[j], acc[i][j], 0, 0, 0);
        acc[i][j] = __builtin_amdgcn_mfma_f32_16x16x32_f16(ah[i], bl[j], acc[i][j], 0, 0, 0);
        acc[i][j] = __builtin_amdgcn_mfma_f32_16x16x32_f16(al[i], bh[j], acc[i][j], 0, 0, 0);
      }
  }
  float* out = sc + (size_t)(hb*HH + h)*SS*SS;
  #pragma unroll
  for (int i=0;i<4;i++){
    #pragma unroll
    for (int r=0;r<4;r++){
      int row = q0 + wr*64 + i*16 + fg*4 + r;
      #pragma unroll
      for (int j=0;j<4;j++){
        int col = k0 + wc*64 + j*16 + fm;
        out[(size_t)row*SS + col] = acc[i][j][r];
      }
    }
  }
}

// ---------------- MFMA PV: ctx[:, h*64..] = P @ V (128q x 64d tiles, BK=64) ----------------
__global__ __launch_bounds__(256) void k_pv_mfma(const float* __restrict__ sc,
                                                 const float* __restrict__ qkv,
                                                 float* __restrict__ ctx, int bbase){
  __shared__ _Float16 Ph[128][SPAD], Pl[128][SPAD];
  __shared__ _Float16 Vh[64][SPAD],  Vl[64][SPAD];
  const int tid = threadIdx.x;
  const int qt = blockIdx.x & 7;
  const int h  = (blockIdx.x >> 3) & 7;
  const int hb = (blockIdx.x >> 6) & 1;
  const int b  = bbase + hb;
  const int q0 = qt*128;
  const float* P = sc + (size_t)(hb*HH + h)*SS*SS;
  const int lane = tid & 63, wid = tid >> 6;
  const int wr = wid >> 1, wc = wid & 1;      // wave tile: 64 rows x 32 cols
  const int fm = lane & 15, fg = lane >> 4;
  f32x4 acc[4][2];
  #pragma unroll
  for (int i=0;i<4;i++){ acc[i][0] = (f32x4){0,0,0,0}; acc[i][1] = (f32x4){0,0,0,0}; }

  for (int kk0=0; kk0<SS; kk0+=64){
    #pragma unroll
    for (int e=0;e<8;e++){
      int lin = e*256 + tid;
      int rr = lin >> 4;
      int c4 = (lin & 15) << 2;
      float4 pv = *reinterpret_cast<const float4*>(P + (size_t)(q0+rr)*SS + kk0 + c4);
      f16x4 ph, pl;
      h2 t;
      t = split2(pv.x); ph[0]=t.hi; pl[0]=t.lo;
      t = split2(pv.y); ph[1]=t.hi; pl[1]=t.lo;
      t = split2(pv.z); ph[2]=t.hi; pl[2]=t.lo;
      t = split2(pv.w); ph[3]=t.hi; pl[3]=t.lo;
      *reinterpret_cast<f16x4*>(&Ph[rr][c4]) = ph;
      *reinterpret_cast<f16x4*>(&Pl[rr][c4]) = pl;
    }
    // stage V transposed: Vh[d][k] = V[kk0+k][d]
    #pragma unroll
    for (int e=0;e<16;e++){
      int lin = e*256 + tid;
      int d = lin & 63;
      int k = lin >> 6;
      float v = qkv[(size_t)(b*SS + kk0+k)*1536 + 1024 + h*64 + d];
      _Float16 hi = (_Float16)v;
      Vh[d][k] = hi;
      Vl[d][k] = (_Float16)(v - (float)hi);
    }
    __syncthreads();
    #pragma unroll
    for (int ks=0; ks<2; ks++){
      f16x8 ah[4], al[4], bh[2], bl[2];
      #pragma unroll
      for (int i=0;i<4;i++){
        int row = wr*64 + i*16 + fm;
        ah[i] = *reinterpret_cast<const f16x8*>(&Ph[row][ks*32 + fg*8]);
        al[i] = *reinterpret_cast<const f16x8*>(&Pl[row][ks*32 + fg*8]);
      }
      #pragma unroll
      for (int j=0;j<2;j++){
        int row = wc*32 + j*16 + fm;
        bh[j] = *reinterpret_cast<const f16x8*>(&Vh[row][ks*32 + fg*8]);
        bl[j] = *reinterpret_cast<const f16x8*>(&Vl[row][ks*32 + fg*8]);
      }
      #pragma unroll
      for (int i=0;i<4;i++)
        #pragma unroll
        for (int j=0;j<2;j++){
          acc[i][j] = __builtin_amdgcn_mfma_f32_16x16x32_f16(ah[i], bh[j], acc[i][j], 0, 0, 0);
          acc[i][j] = __builtin_amdgcn_mfma_f32_16x16x32_f16(ah[i], bl[j], acc[i][j], 0, 0, 0);
          acc[i][j] = __builtin_amdgcn_mfma_f32_16x16x32_f16(al[i], bh[j], acc[i][j], 0, 0, 0);
        }
    }
    __syncthreads();
  }
  #pragma unroll
  for (int i=0;i<4;i++){
    #pragma unroll
    for (int r=0;r<4;r++){
      int row = q0 + wr*64 + i*16 + fg*4 + r;
      #pragma unroll
      for (int j=0;j<2;j++){
        int col = wc*32 + j*16 + fm;
        ctx[(size_t)(b*SS + row)*DD + h*64 + col] = acc[i][j][r];
      }
    }
  }
}

// ---------------- persistent LSTM: 256 blocks = 4 batches x 64 chunks(8 dims) ----------------
// Dataflow sync via packed 64-bit {tag|h} relaxed agent-scope atomics.
__global__ __launch_bounds__(256) void k_lstm(const float* __restrict__ gates_in,
                                              const float* __restrict__ w_hh,
                                              unsigned long long* __restrict__ hpack){
  __shared__ float hsh[DD];
  __shared__ float gl[32];
  const int b = blockIdx.x >> 6;
  const int chunk = blockIdx.x & 63;
  const int d0 = chunk*8;
  const int tid = threadIdx.x;
  const int r = tid >> 3;        // 0..31 : local row = gate*8 + di
  const int ks = tid & 7;        // interleaved k-slice
  const int gate = r >> 3;
  const int di = r & 7;
  float w[64];
  {
    const float* wrow = w_hh + (size_t)(gate*DD + d0 + di)*DD;
    #pragma unroll
    for (int j=0;j<64;j++) w[j] = wrow[j*8 + ks];
  }
  float c = 0.0f;
  const float* gbase = gates_in + (size_t)(b*SS)*(4*DD) + gate*DD + d0 + di;
  for (int t=0; t<SS; ++t){
    float gv = 0.0f;
    if (ks == 0) gv = gbase[(size_t)t*(4*DD)];
    unsigned long long* hp = hpack + (size_t)(t*BB + b)*DD;
    const unsigned long long exp_tag = (unsigned long long)t;
    unsigned long long p0 = __hip_atomic_load(hp + tid,       __ATOMIC_RELAXED, __HIP_MEMORY_SCOPE_AGENT);
    unsigned long long p1 = __hip_atomic_load(hp + tid + 256, __ATOMIC_RELAXED, __HIP_MEMORY_SCOPE_AGENT);
    while ((p0 >> 32) != exp_tag || (p1 >> 32) != exp_tag){
      __builtin_amdgcn_s_sleep(1);
      if ((p0 >> 32) != exp_tag)
        p0 = __hip_atomic_load(hp + tid,       __ATOMIC_RELAXED, __HIP_MEMORY_SCOPE_AGENT);
      if ((p1 >> 32) != exp_tag)
        p1 = __hip_atomic_load(hp + tid + 256, __ATOMIC_RELAXED, __HIP_MEMORY_SCOPE_AGENT);
    }
    union { unsigned int u; float f; } u0, u1;
    u0.u = (unsigned int)p0;
    u1.u = (unsigned int)p1;
    hsh[tid]       = u0.f;
    hsh[tid + 256] = u1.f;
    __syncthreads();
    float a0=0.0f, a1=0.0f, a2=0.0f, a3=0.0f;
    #pragma unroll
    for (int j=0;j<64;j+=4){
      a0 += w[j+0]*hsh[(j+0)*8 + ks];
      a1 += w[j+1]*hsh[(j+1)*8 + ks];
      a2 += w[j+2]*hsh[(j+2)*8 + ks];
      a3 += w[j+3]*hsh[(j+3)*8 + ks];
    }
    float acc = (a0+a1)+(a2+a3);
    acc += __shfl_down(acc, 4, 8);
    acc += __shfl_down(acc, 2, 8);
    acc += __shfl_down(acc, 1, 8);
    if (ks == 0){
      float v = acc + gv;
      gl[r] = (gate == 2) ? ftanh(v) : fsig(v);   // pre-activated gate
    }
    __syncthreads();
    if (tid < 8){
      float gi = gl[tid];
      float gf = gl[8 + tid];
      float gg = gl[16 + tid];
      float go = gl[24 + tid];
      c = gf*c + gi*gg;
      float h = go*ftanh(c);
      union { float f; unsigned int u; } hu; hu.f = h;
      unsigned long long pk = ((unsigned long long)(unsigned int)(t+1) << 32)
                            | (unsigned long long)hu.u;
      __hip_atomic_store(&hpack[(size_t)((t+1)*BB + b)*DD + d0 + tid], pk,
                         __ATOMIC_RELAXED, __HIP_MEMORY_SCOPE_AGENT);
    }
  }
}

__global__ void k_resid(float* __restrict__ x, const unsigned long long* __restrict__ hpack){
  int idx = blockIdx.x*256 + threadIdx.x;
  if (idx >= NT*DD) return;
  int d = idx & (DD-1);
  int n = idx >> 9;
  int s = n & (SS-1);
  int b = n >> 10;
  union { unsigned int u; float f; } hu;
  hu.u = (unsigned int)hpack[(size_t)((s+1)*BB + b)*DD + d];
  x[idx] += hu.f;
}

__device__ __forceinline__ float blockReduce(float v, float* red, int tid, int isMax){
  #pragma unroll
  for (int o=32;o>0;o>>=1){
    float t = __shfl_xor(v, o);
    v = isMax ? fmaxf(v, t) : v + t;
  }
  if ((tid & 63) == 0) red[tid >> 6] = v;
  __syncthreads();
  float r = red[0];
  #pragma unroll
  for (int i=1;i<4;i++) r = isMax ? fmaxf(r, red[i]) : r + red[i];
  __syncthreads();
  return r;
}

// softmax rows in place + accumulate head-average into d_out attn region
__global__ __launch_bounds__(256) void k_softmax(float* __restrict__ sc,
                                                 float* __restrict__ attn_out,
                                                 int l, int bbase){
  __shared__ float avg[SS];
  __shared__ float red[8];
  const int tid = threadIdx.x;
  const int q  = blockIdx.x & (SS-1);
  const int hb = blockIdx.x >> 10;
  const int b = bbase + hb;
  for (int j=tid;j<SS;j+=256) avg[j] = 0.0f;
  __syncthreads();
  for (int h=0;h<HH;h++){
    float* row = sc + (size_t)(hb*HH + h)*SS*SS + (size_t)q*SS;
    float v[4];
    float m = -1e30f;
    #pragma unroll
    for (int j=0;j<4;j++){ v[j] = row[tid + j*256]; m = fmaxf(m, v[j]); }
    m = blockReduce(m, red, tid, 1);
    float s = 0.0f;
    #pragma unroll
    for (int j=0;j<4;j++){ v[j] = __expf(v[j] - m); s += v[j]; }
    s = blockReduce(s, red, tid, 0);
    float inv = __builtin_amdgcn_rcpf(s);
    #pragma unroll
    for (int j=0;j<4;j++){
      float p = v[j]*inv;
      row[tid + j*256] = p;
      avg[tid + j*256] += p;
    }
    __syncthreads();
  }
  float* ao = attn_out + (size_t)((l*BB + b)*SS + q)*SS;
  for (int j=tid;j<SS;j+=256) ao[j] = avg[j]*0.125f;
}

// ---------------- LayerNorm: out = LN(x (+ y)) * g + b ----------------
__global__ __launch_bounds__(64) void k_ln(const float* __restrict__ x,
                                           const float* __restrict__ y,
                                           const float* __restrict__ g,
                                           const float* __restrict__ bta,
                                           float* __restrict__ out){
  const int n = blockIdx.x;
  const int tid = threadIdx.x;
  float v[8];
  float s = 0.0f, sq = 0.0f;
  #pragma unroll
  for (int j=0;j<8;j++){
    int d = j*64 + tid;
    float a = x[(size_t)n*DD + d];
    if (y) a += y[(size_t)n*DD + d];
    v[j] = a; s += a; sq += a*a;
  }
  #pragma unroll
  for (int o=32;o>0;o>>=1){ s += __shfl_xor(s, o); sq += __shfl_xor(sq, o); }
  float mean = s*(1.0f/DD);
  float var = sq*(1.0f/DD) - mean*mean;
  float rstd = rsqrtf(var + EPSF);
  #pragma unroll
  for (int j=0;j<8;j++){
    int d = j*64 + tid;
    out[(size_t)n*DD + d] = (v[j]-mean)*rstd*g[d] + bta[d];
  }
}

extern "C" void kernel_launch(void* const* d_in, const int* in_sizes, int n_in,
                              void* d_out, int out_size, void* d_ws, size_t ws_size,
                              hipStream_t stream){
  const int*   src    = (const int*)  d_in[0];
  const float* emb    = (const float*)d_in[1];
  const float* conv_w = (const float*)d_in[2];
  const float* conv_b = (const float*)d_in[3];
  const float* bn_g   = (const float*)d_in[4];
  const float* bn_b   = (const float*)d_in[5];
  const float* bn_m   = (const float*)d_in[6];
  const float* bn_v   = (const float*)d_in[7];
  const float* w_ih   = (const float*)d_in[8];
  const float* w_hh   = (const float*)d_in[9];
  const float* b_ih   = (const float*)d_in[10];
  const float* b_hh   = (const float*)d_in[11];
  const float* in_w   = (const float*)d_in[12];
  const float* in_b   = (const float*)d_in[13];
  const float* out_w  = (const float*)d_in[14];
  const float* out_b  = (const float*)d_in[15];
  const float* ln1_g  = (const float*)d_in[16];
  const float* ln1_b  = (const float*)d_in[17];
  const float* w1     = (const float*)d_in[18];
  const float* b1     = (const float*)d_in[19];
  const float* w2     = (const float*)d_in[20];
  const float* b2     = (const float*)d_in[21];
  const float* ln2_g  = (const float*)d_in[22];
  const float* ln2_b  = (const float*)d_in[23];
  const float* fin_g  = (const float*)d_in[24];
  const float* fin_b  = (const float*)d_in[25];

  float* ws    = (float*)d_ws;
  float* x0    = ws + O_X0;
  float* x1    = ws + O_X1;
  float* ctx   = ws + O_CTX;
  float* qkv   = ws + O_QKV;
  float* big   = ws + O_BIG;     // gates (low 8.39M) / scores / ffh
  float* bsum  = ws + O_BSUM;
  unsigned long long* hpack = (unsigned long long*)(big + 8388608);

  float* outx  = (float*)d_out;            // [B,S,D]
  float* attn  = outx + (size_t)NT*DD;     // [L,B,S,S]

  hipMemsetAsync(hpack, 0, (size_t)(SS+1)*BB*DD*sizeof(unsigned long long), stream);

  const int eb = (NT*DD)/256;
  k_embed<<<eb, 256, 0, stream>>>(src, emb, x0);
  k_conv <<<eb, 256, 0, stream>>>(x0, conv_w, conv_b, bn_g, bn_b, bn_m, bn_v, x1);
  k_bsum <<<8, 256, 0, stream>>>(b_ih, b_hh, bsum, 4*DD);

  // LSTM input precompute: gates = x1 @ w_ih^T + (b_ih + b_hh)
  k_gemm_mfma<0><<<(NT/128)*((4*DD)/128), 256, 0, stream>>>(
      x1, w_ih, bsum, big, NT, 4*DD, DD);
  k_lstm<<<256, 256, 0, stream>>>(big, w_hh, hpack);
  k_resid<<<eb, 256, 0, stream>>>(x1, hpack);

  float* cur = x1;
  float* tmp = x0;
  for (int l=0; l<LL; ++l){
    // qkv = cur @ in_w[l]^T + in_b[l]
    k_gemm_mfma<0><<<(NT/128)*(1536/128), 256, 0, stream>>>(
        cur, in_w + (size_t)l*1536*DD, in_b + (size_t)l*1536, qkv, NT, 1536, DD);
    for (int bb2=0; bb2<2; ++bb2){
      int bbase = bb2*2;
      k_scores_mfma<<<1024, 256, 0, stream>>>(qkv, big, bbase);
      k_softmax    <<<2048, 256, 0, stream>>>(big, attn, l, bbase);
      k_pv_mfma    <<<128,  256, 0, stream>>>(big, qkv, ctx, bbase);
    }
    // proj: tmp = ctx @ out_w[l]^T + out_b[l]
    k_gemm_mfma<0><<<(NT/128)*(DD/128), 256, 0, stream>>>(
        ctx, out_w + (size_t)l*DD*DD, out_b + (size_t)l*DD, tmp, NT, DD, DD);
    k_ln<<<NT, 64, 0, stream>>>(cur, tmp, ln1_g + l*DD, ln1_b + l*DD, cur);
    // ffh = gelu(cur @ w1[l]^T + b1[l])
    k_gemm_mfma<1><<<(NT/128)*(DFF/128), 256, 0, stream>>>(
        cur, w1 + (size_t)l*DFF*DD, b1 + (size_t)l*DFF, big, NT, DFF, DD);
    // tmp = ffh @ w2[l]^T + b2[l]
    k_gemm_mfma<0><<<(NT/128)*(DD/128), 256, 0, stream>>>(
        big, w2 + (size_t)l*DD*DFF, b2 + (size_t)l*DD, tmp, NT, DD, DFF);
    k_ln<<<NT, 64, 0, stream>>>(cur, tmp, ln2_g + l*DD, ln2_b + l*DD, cur);
  }
  k_ln<<<NT, 64, 0, stream>>>(cur, nullptr, fin_g, fin_b, outx);
}